// Round 10
// baseline (299.396 us; speedup 1.0000x reference)
//
#include <hip/hip_runtime.h>
#include <hip/hip_bf16.h>

#define N_NODES 100000
#define N_EDGES 1600000
#define IN_DIM 128
#define HID_DIM 64
#define EMB_DIM 64
#define OUT_DIM 40
#define NTILES 6250   // N_NODES / 16
#define NB 391        // dst buckets of 256 nodes
#define DEPTH 24
#define DSTRIDE 25    // lbuf pitch (odd -> conflict-free)
#define CAP 5120      // per-bucket capacity (mean 4096, ~16 sigma headroom)

typedef __attribute__((ext_vector_type(8))) short bf16x8;
typedef __attribute__((ext_vector_type(4))) float f32x4;
typedef __attribute__((ext_vector_type(4))) unsigned int u32x4;

__device__ __forceinline__ float bf2f(unsigned short u) {
    unsigned int v = ((unsigned int)u) << 16;
    float f;
    __builtin_memcpy(&f, &v, 4);
    return f;
}
__device__ __forceinline__ float u32f(unsigned int v) {
    float f;
    __builtin_memcpy(&f, &v, 4);
    return f;
}
__device__ __forceinline__ unsigned short f2bf(float f) {
    __hip_bfloat16 b = __float2bfloat16(f);
    unsigned short u;
    __builtin_memcpy(&u, &b, 2);
    return u;
}

// flags[0]: 1 = float tensors are bf16, 0 = fp32
// flags[1]: 1 = edge_index is int64, 0 = int32
__device__ __forceinline__ float loadf(const void* p, size_t i, int isbf) {
    return isbf ? bf2f(((const unsigned short*)p)[i]) : ((const float*)p)[i];
}
__device__ __forceinline__ int loadi(const void* p, size_t i, int is64) {
    return is64 ? (int)(((const long long*)p)[i]) : ((const int*)p)[i];
}

// ---- dtype detection ----
__global__ void k_detect(const unsigned int* __restrict__ xb,
                         const unsigned int* __restrict__ eib,
                         int* __restrict__ flags) {
    int tid = threadIdx.x;
    unsigned int u = xb[tid];
    unsigned int lo_exp = (u >> 7) & 0xFF;
    bool bfplaus = (lo_exp >= 100 && lo_exp <= 140) || ((u & 0xFFFFu) == 0u);
    unsigned long long m1 = __ballot(bfplaus);
    unsigned int hi = eib[2 * tid + 1];
    unsigned long long m2 = __ballot(hi == 0u);
    if (tid == 0) {
        flags[0] = (__popcll(m1) >= 48) ? 1 : 0;
        flags[1] = (m2 == 0xFFFFFFFFFFFFFFFFULL) ? 1 : 0;
    }
}

// gcur[b] = b*CAP
__global__ void k_ginit(int* __restrict__ gcur) {
    int b = blockIdx.x * blockDim.x + threadIdx.x;
    if (b < NB) gcur[b] = b * CAP;
}

// ---- phase 1: barrier-free LDS-staged multi-split into fixed-capacity dst-buckets ----
// binned[p] = (dst_local << 24) | src
__global__ __launch_bounds__(256) void k_bin(const void* __restrict__ ei,
                                             int* __restrict__ gcur,
                                             unsigned int* __restrict__ binned,
                                             const int* __restrict__ flags, int E) {
    __shared__ unsigned int lbuf[NB * DSTRIDE];  // ~39 KB
    __shared__ int lcnt[NB];
    __shared__ int pcur[NB];
    int is64 = flags[1];
    int tid = threadIdx.x;
    for (int b = tid; b < NB; b += 256) lcnt[b] = 0;
    __syncthreads();
    int per = (E + gridDim.x - 1) / gridDim.x;
    int e0 = blockIdx.x * per;
    int e1 = min(e0 + per, E);
    // classify: NO barriers in this loop
    for (int e = e0 + tid; e < e1; e += 256) {
        int s = loadi(ei, e, is64);
        int d = loadi(ei, (size_t)N_EDGES + e, is64);
        int b = d >> 8;
        unsigned int val = ((unsigned int)(d & 255) << 24) | (unsigned int)s;
        int slot = atomicAdd(&lcnt[b], 1);
        if (slot < DEPTH) {
            lbuf[b * DSTRIDE + slot] = val;
        } else {  // rare overflow: direct write
            int p = atomicAdd(&gcur[b], 1);
            if (p < (b + 1) * CAP) binned[p] = val;
        }
    }
    __syncthreads();
    // reserve drain regions (all atomics pipelined)
    for (int b = tid; b < NB; b += 256) {
        int c = min(lcnt[b], DEPTH);
        pcur[b] = c ? atomicAdd(&gcur[b], c) : 0;
    }
    __syncthreads();
    // wave-cooperative drain: lane j copies entry j of each bucket
    int lane = tid & 63, wv = tid >> 6;
    for (int b = wv; b < NB; b += 4) {
        int c = min(lcnt[b], DEPTH);
        if (lane < c) {
            int p = pcur[b] + lane;
            if (p < (b + 1) * CAP) binned[p] = lbuf[b * DSTRIDE + lane];
        }
    }
}

// ---- scan bucket totals -> btot (exclusive), rs[N]=E ----
__global__ void k_bscan(const int* __restrict__ gcur, int* __restrict__ btot,
                        int* __restrict__ rs) {
    __shared__ int sh[512];
    int t = threadIdx.x;
    int v = 0;
    if (t < NB) {
        v = gcur[t] - t * CAP;
        if (v > CAP) v = CAP;
    }
    sh[t] = v;
    __syncthreads();
    for (int o = 1; o < 512; o <<= 1) {
        int u = (t >= o) ? sh[t - o] : 0;
        __syncthreads();
        sh[t] += u;
        __syncthreads();
    }
    if (t < NB) btot[t] = sh[t] - v;
    if (t == NB) rs[N_NODES] = N_EDGES;
}

// ---- phase 2: per bucket, count per node, scan, write rs/dinv + exact CSR ----
__global__ __launch_bounds__(512) void k_regroup(const unsigned int* __restrict__ binned,
                                                 const int* __restrict__ btot,
                                                 const int* __restrict__ gcur,
                                                 int* __restrict__ csr_src,
                                                 int* __restrict__ rs,
                                                 float* __restrict__ dinv) {
    __shared__ int lcnt[256];
    __shared__ int lofs[256];
    int b = blockIdx.x, tid = threadIdx.x;
    int n0 = b * 256;
    int nn = min(256, N_NODES - n0);
    if (tid < 256) lcnt[tid] = 0;
    __syncthreads();
    int src0 = b * CAP;
    int m = gcur[b] - src0;
    if (m > CAP) m = CAP;
    for (int i = tid; i < m; i += 512) {
        atomicAdd(&lcnt[binned[src0 + i] >> 24], 1);
    }
    __syncthreads();
    int c = 0;
    if (tid < 256) { c = lcnt[tid]; lofs[tid] = c; }
    __syncthreads();
    for (int o = 1; o < 256; o <<= 1) {
        int u = (tid < 256 && tid >= o) ? lofs[tid - o] : 0;
        __syncthreads();
        if (tid < 256) lofs[tid] += u;
        __syncthreads();
    }
    int base = btot[b];
    if (tid < 256) {
        int mystart = base + lofs[tid] - c;
        if (tid < nn) {
            rs[n0 + tid] = mystart;
            dinv[n0 + tid] = rsqrtf(1.0f + (float)c);
        }
        lofs[tid] = mystart;  // reuse as cursors
    }
    __syncthreads();
    for (int i = tid; i < m; i += 512) {
        unsigned int v = binned[src0 + i];
        int p = atomicAdd(&lofs[v >> 24], 1);
        csr_src[p] = v & 0xFFFFFF;
    }
}

// ---- MFMA GEMM1: g[N,64] = bf16( dinv[r] * (x[N,128] @ W1[128,64]) ) ----
__global__ __launch_bounds__(256) void k_gemm1(const void* __restrict__ x,
                                               const void* __restrict__ W1,
                                               const float* __restrict__ dinv,
                                               unsigned short* __restrict__ out,
                                               const int* __restrict__ flags, int n) {
    __shared__ unsigned short W1T[64 * 136];
    int isbf = flags[0];
    int tid = threadIdx.x;
    for (int i = tid; i < IN_DIM * HID_DIM; i += 256) {
        int k = i >> 6, nn = i & 63;
        W1T[nn * 136 + k] = isbf ? ((const unsigned short*)W1)[i] : f2bf(((const float*)W1)[i]);
    }
    __syncthreads();
    int lane = tid & 63;
    int lane16 = lane & 15, quad = lane >> 4;
    bf16x8 bfrag[4][4];
#pragma unroll
    for (int ct = 0; ct < 4; ++ct)
#pragma unroll
        for (int kc = 0; kc < 4; ++kc)
            bfrag[ct][kc] = *(const bf16x8*)&W1T[(ct * 16 + lane16) * 136 + kc * 32 + quad * 8];
    int wid = (blockIdx.x * 256 + tid) >> 6;
    int nw = (gridDim.x * 256) >> 6;
    for (int t = wid; t < NTILES; t += nw) {
        int row0 = t * 16;
        bf16x8 afrag[4];
        if (isbf) {
            const unsigned short* xr = (const unsigned short*)x + (size_t)(row0 + lane16) * IN_DIM;
#pragma unroll
            for (int kc = 0; kc < 4; ++kc)
                afrag[kc] = *(const bf16x8*)(xr + kc * 32 + quad * 8);
        } else {
            const float* xr = (const float*)x + (size_t)(row0 + lane16) * IN_DIM;
#pragma unroll
            for (int kc = 0; kc < 4; ++kc) {
                f32x4 p0 = *(const f32x4*)(xr + kc * 32 + quad * 8);
                f32x4 p1 = *(const f32x4*)(xr + kc * 32 + quad * 8 + 4);
                bf16x8 a;
#pragma unroll
                for (int j = 0; j < 4; ++j) {
                    a[j] = (short)f2bf(p0[j]);
                    a[4 + j] = (short)f2bf(p1[j]);
                }
                afrag[kc] = a;
            }
        }
        f32x4 acc[4] = {};
#pragma unroll
        for (int kc = 0; kc < 4; ++kc)
#pragma unroll
            for (int ct = 0; ct < 4; ++ct)
                acc[ct] = __builtin_amdgcn_mfma_f32_16x16x32_bf16(afrag[kc], bfrag[ct][kc], acc[ct], 0, 0, 0);
        float dv[4];
#pragma unroll
        for (int r = 0; r < 4; ++r) dv[r] = dinv[row0 + quad * 4 + r];
#pragma unroll
        for (int ct = 0; ct < 4; ++ct)
#pragma unroll
            for (int r = 0; r < 4; ++r)
                out[(size_t)(row0 + quad * 4 + r) * HID_DIM + ct * 16 + lane16] = f2bf(acc[ct][r] * dv[r]);
    }
}

// gather aggregation v2: 8 lanes/edge, 16B loads, 8 edges in flight; bf16 out
// out[d] = bf16( dinv[d] * ( g[d] + sum_{s in row d} g[s] ) ), g pre-scaled by dinv[s]
__global__ __launch_bounds__(256) void k_aggregate(const unsigned short* __restrict__ g,
                                                   const float* __restrict__ dinv,
                                                   const int* __restrict__ rs,
                                                   const int* __restrict__ csr_src,
                                                   unsigned short* __restrict__ out, int n) {
    int lane = threadIdx.x & 63;
    int grp = lane >> 3;   // which edge slot (0..7)
    int sub = lane & 7;    // which 16B chunk of the row (0..7)
    int node = blockIdx.x * 4 + (threadIdx.x >> 6);
    if (node >= n) return;
    int start = rs[node];
    int m_all = rs[node + 1] - start;
    const u32x4* g4 = (const u32x4*)g;
    float acc[8] = {0.f, 0.f, 0.f, 0.f, 0.f, 0.f, 0.f, 0.f};
    for (int base = 0; base < m_all; base += 64) {
        int m = min(64, m_all - base);
        int idx = (lane < m) ? csr_src[start + base + lane] : 0;
        int nIt = (m + 7) >> 3;
        for (int it = 0; it < nIt; ++it) {
            int j = it * 8 + grp;
            int s = __shfl(idx, j);
            float w = (j < m) ? 1.0f : 0.0f;
            u32x4 p = g4[(size_t)s * 8 + sub];
#pragma unroll
            for (int q = 0; q < 4; ++q) {
                unsigned int u = p[q];
                acc[2 * q]     = fmaf(w, u32f(u << 16), acc[2 * q]);
                acc[2 * q + 1] = fmaf(w, u32f(u & 0xFFFF0000u), acc[2 * q + 1]);
            }
        }
    }
#pragma unroll
    for (int off = 8; off <= 32; off <<= 1)
#pragma unroll
        for (int q = 0; q < 8; ++q) acc[q] += __shfl_xor(acc[q], off);
    if (grp == 0) {  // lanes 0..7 hold the full row: lane sub -> cols sub*8..sub*8+7
        u32x4 ps = g4[(size_t)node * 8 + sub];
        float dd = dinv[node];
        u32x4 ov;
#pragma unroll
        for (int q = 0; q < 4; ++q) {
            float lo = (acc[2 * q]     + u32f(ps[q] << 16)) * dd;
            float hi = (acc[2 * q + 1] + u32f(ps[q] & 0xFFFF0000u)) * dd;
            ov[q] = (unsigned int)f2bf(lo) | ((unsigned int)f2bf(hi) << 16);
        }
        ((u32x4*)out)[(size_t)node * 8 + sub] = ov;
    }
}

// ---- MFMA GEMM2: g2[N,64] = bf16( dinv[r] * (relu(in[N,64]+b1) @ W2[64,64]) ), in is bf16 ----
__global__ __launch_bounds__(256) void k_gemm2(const unsigned short* __restrict__ in,
                                               const void* __restrict__ W2,
                                               const void* __restrict__ b1,
                                               const float* __restrict__ dinv,
                                               unsigned short* __restrict__ out,
                                               const int* __restrict__ flags, int n) {
    __shared__ unsigned short W2T[64 * 72];
    __shared__ float bs[64];
    int isbf = flags[0];
    int tid = threadIdx.x;
    for (int i = tid; i < HID_DIM * EMB_DIM; i += 256) {
        int k = i >> 6, nn = i & 63;
        W2T[nn * 72 + k] = isbf ? ((const unsigned short*)W2)[i] : f2bf(((const float*)W2)[i]);
    }
    if (tid < 64) bs[tid] = loadf(b1, tid, isbf);
    __syncthreads();
    int lane = tid & 63;
    int lane16 = lane & 15, quad = lane >> 4;
    bf16x8 bfrag[4][2];
#pragma unroll
    for (int ct = 0; ct < 4; ++ct)
#pragma unroll
        for (int kc = 0; kc < 2; ++kc)
            bfrag[ct][kc] = *(const bf16x8*)&W2T[(ct * 16 + lane16) * 72 + kc * 32 + quad * 8];
    float bv[2][8];
#pragma unroll
    for (int kc = 0; kc < 2; ++kc)
#pragma unroll
        for (int j = 0; j < 8; ++j) bv[kc][j] = bs[kc * 32 + quad * 8 + j];
    int wid = (blockIdx.x * 256 + tid) >> 6;
    int nw = (gridDim.x * 256) >> 6;
    for (int t = wid; t < NTILES; t += nw) {
        int row0 = t * 16;
        const unsigned short* ir = in + (size_t)(row0 + lane16) * HID_DIM;
        bf16x8 afrag[2];
#pragma unroll
        for (int kc = 0; kc < 2; ++kc) {
            bf16x8 raw = *(const bf16x8*)(ir + kc * 32 + quad * 8);
            bf16x8 a;
#pragma unroll
            for (int j = 0; j < 8; ++j) {
                float f = fmaxf(bf2f((unsigned short)raw[j]) + bv[kc][j], 0.0f);
                a[j] = (short)f2bf(f);
            }
            afrag[kc] = a;
        }
        f32x4 acc[4] = {};
#pragma unroll
        for (int kc = 0; kc < 2; ++kc)
#pragma unroll
            for (int ct = 0; ct < 4; ++ct)
                acc[ct] = __builtin_amdgcn_mfma_f32_16x16x32_bf16(afrag[kc], bfrag[ct][kc], acc[ct], 0, 0, 0);
        float dv[4];
#pragma unroll
        for (int r = 0; r < 4; ++r) dv[r] = dinv[row0 + quad * 4 + r];
#pragma unroll
        for (int ct = 0; ct < 4; ++ct)
#pragma unroll
            for (int r = 0; r < 4; ++r)
                out[(size_t)(row0 + quad * 4 + r) * EMB_DIM + ct * 16 + lane16] = f2bf(acc[ct][r] * dv[r]);
    }
}

// ---- MFMA head: logits = (in+b2) @ Wl + bl ; log_softmax ; in is bf16 ----
__global__ __launch_bounds__(256) void k_final(const unsigned short* __restrict__ in,
                                               const void* __restrict__ b2,
                                               const void* __restrict__ Wl,
                                               const void* __restrict__ bl,
                                               void* __restrict__ out,
                                               const int* __restrict__ flags, int n) {
    __shared__ unsigned short WlT[48 * 72];
    __shared__ float b2s[64];
    int isbf = flags[0];
    int tid = threadIdx.x;
    for (int i = tid; i < 48 * 64; i += 256) {
        int nn = i >> 6, k = i & 63;
        WlT[nn * 72 + k] = (nn < OUT_DIM) ?
            (isbf ? ((const unsigned short*)Wl)[k * OUT_DIM + nn] : f2bf(((const float*)Wl)[k * OUT_DIM + nn]))
            : (unsigned short)0;
    }
    if (tid < 64) b2s[tid] = loadf(b2, tid, isbf);
    __syncthreads();
    int lane = tid & 63;
    int lane16 = lane & 15, quad = lane >> 4;
    bf16x8 bfrag[3][2];
#pragma unroll
    for (int ct = 0; ct < 3; ++ct)
#pragma unroll
        for (int kc = 0; kc < 2; ++kc)
            bfrag[ct][kc] = *(const bf16x8*)&WlT[(ct * 16 + lane16) * 72 + kc * 32 + quad * 8];
    float b2v[2][8];
#pragma unroll
    for (int kc = 0; kc < 2; ++kc)
#pragma unroll
        for (int j = 0; j < 8; ++j) b2v[kc][j] = b2s[kc * 32 + quad * 8 + j];
    float blv[3];
    bool v2 = (lane16 < 8);
#pragma unroll
    for (int ct = 0; ct < 3; ++ct) {
        int col = ct * 16 + lane16;
        blv[ct] = (col < OUT_DIM) ? loadf(bl, col, isbf) : 0.0f;
    }
    int wid = (blockIdx.x * 256 + tid) >> 6;
    int nw = (gridDim.x * 256) >> 6;
    for (int t = wid; t < NTILES; t += nw) {
        int row0 = t * 16;
        const unsigned short* ir = in + (size_t)(row0 + lane16) * EMB_DIM;
        bf16x8 afrag[2];
#pragma unroll
        for (int kc = 0; kc < 2; ++kc) {
            bf16x8 raw = *(const bf16x8*)(ir + kc * 32 + quad * 8);
            bf16x8 a;
#pragma unroll
            for (int j = 0; j < 8; ++j) {
                float f = bf2f((unsigned short)raw[j]) + b2v[kc][j];
                a[j] = (short)f2bf(f);
            }
            afrag[kc] = a;
        }
        f32x4 acc[3] = {};
#pragma unroll
        for (int kc = 0; kc < 2; ++kc)
#pragma unroll
            for (int ct = 0; ct < 3; ++ct)
                acc[ct] = __builtin_amdgcn_mfma_f32_16x16x32_bf16(afrag[kc], bfrag[ct][kc], acc[ct], 0, 0, 0);
#pragma unroll
        for (int r = 0; r < 4; ++r) {
            float l0 = acc[0][r] + blv[0];
            float l1 = acc[1][r] + blv[1];
            float l2 = v2 ? (acc[2][r] + blv[2]) : -INFINITY;
            float mx = fmaxf(fmaxf(l0, l1), l2);
#pragma unroll
            for (int s = 1; s < 16; s <<= 1) mx = fmaxf(mx, __shfl_xor(mx, s));
            float sm = expf(l0 - mx) + expf(l1 - mx) + (v2 ? expf(l2 - mx) : 0.0f);
#pragma unroll
            for (int s = 1; s < 16; s <<= 1) sm += __shfl_xor(sm, s);
            float ls = mx + logf(sm);
            int row = row0 + quad * 4 + r;
            size_t o = (size_t)row * OUT_DIM;
            if (isbf) {
                __hip_bfloat16* ob = (__hip_bfloat16*)out;
                ob[o + lane16] = __float2bfloat16(l0 - ls);
                ob[o + 16 + lane16] = __float2bfloat16(l1 - ls);
                if (v2) ob[o + 32 + lane16] = __float2bfloat16(l2 - ls);
            } else {
                float* of = (float*)out;
                of[o + lane16] = l0 - ls;
                of[o + 16 + lane16] = l1 - ls;
                if (v2) of[o + 32 + lane16] = l2 - ls;
            }
        }
    }
}

extern "C" void kernel_launch(void* const* d_in, const int* in_sizes, int n_in,
                              void* d_out, int out_size, void* d_ws, size_t ws_size,
                              hipStream_t stream) {
    const void* x  = d_in[0];
    const void* ei = d_in[1];
    const void* W1 = d_in[2];
    const void* b1 = d_in[3];
    const void* W2 = d_in[4];
    const void* b2 = d_in[5];
    const void* Wl = d_in[6];
    const void* bl = d_in[7];

    float* ws = (float*)d_ws;
    // layout (float-slot offsets). NOTE: N*64 bf16 = 6.4M ushorts = 3,200,000 FLOAT slots.
    int*   flags   = (int*)ws;                             // [0, 64)
    float* dinv    = ws + 64;                              // [64, 100064) pad -> 100096
    int*   rs      = (int*)(ws + 100096);                  // N+1 ints, pad -> 200224
    int*   btot    = (int*)(ws + 200224);                  // [200224, 200736)
    int*   gcur    = (int*)(ws + 200736);                  // [200736, 201248)
    int*   csr_src = (int*)(ws + 201248);                  // E ints -> [201248, 1801248)
    unsigned short* g      = (unsigned short*)(ws + 1801248); // bf16 [1801248, 5001248)
    unsigned short* aggout = (unsigned short*)(ws + 5001248); // bf16 [5001248, 8201248)
    unsigned int* binned   = (unsigned int*)(ws + 1801248);   // NB*CAP ints [1801248, 3803168)
                                                              // aliases g only; dead before k_gemm1
    // total ws: 8,201,248 floats = 32.8 MB

    k_detect<<<1, 64, 0, stream>>>((const unsigned int*)x, (const unsigned int*)ei, flags);

    // CSR build: bin (barrier-free) -> bucket scan -> regroup (counts+scan+fill+rs+dinv)
    k_ginit<<<2, 256, 0, stream>>>(gcur);
    k_bin<<<512, 256, 0, stream>>>(ei, gcur, binned, flags, N_EDGES);
    k_bscan<<<1, 512, 0, stream>>>(gcur, btot, rs);
    k_regroup<<<NB, 512, 0, stream>>>(binned, btot, gcur, csr_src, rs, dinv);

    // layer 1
    k_gemm1<<<1280, 256, 0, stream>>>(x, W1, dinv, g, flags, N_NODES);
    k_aggregate<<<25000, 256, 0, stream>>>(g, dinv, rs, csr_src, aggout, N_NODES);

    // layer 2
    k_gemm2<<<1280, 256, 0, stream>>>(aggout, W2, b1, dinv, g, flags, N_NODES);
    k_aggregate<<<25000, 256, 0, stream>>>(g, dinv, rs, csr_src, aggout, N_NODES);

    // head
    k_final<<<1280, 256, 0, stream>>>(aggout, b2, Wl, bl, d_out, flags, N_NODES);
}

// Round 11
// 286.267 us; speedup vs baseline: 1.0459x; 1.0459x over previous
//
#include <hip/hip_runtime.h>
#include <hip/hip_bf16.h>

#define N_NODES 100000
#define N_EDGES 1600000
#define IN_DIM 128
#define HID_DIM 64
#define EMB_DIM 64
#define OUT_DIM 40
#define NTILES 6250   // N_NODES / 16
#define NB 391        // dst buckets of 256 nodes
#define DEPTH 24
#define DSTRIDE 25    // lbuf pitch (odd -> conflict-free)
#define CAP 5120      // per-bucket capacity (mean 4096, ~16 sigma headroom)

typedef __attribute__((ext_vector_type(8))) short bf16x8;
typedef __attribute__((ext_vector_type(4))) float f32x4;
typedef __attribute__((ext_vector_type(4))) unsigned int u32x4;

__device__ __forceinline__ float bf2f(unsigned short u) {
    unsigned int v = ((unsigned int)u) << 16;
    float f;
    __builtin_memcpy(&f, &v, 4);
    return f;
}
__device__ __forceinline__ float u32f(unsigned int v) {
    float f;
    __builtin_memcpy(&f, &v, 4);
    return f;
}
__device__ __forceinline__ unsigned short f2bf(float f) {
    __hip_bfloat16 b = __float2bfloat16(f);
    unsigned short u;
    __builtin_memcpy(&u, &b, 2);
    return u;
}

// flags[0]: 1 = float tensors are bf16, 0 = fp32
// flags[1]: 1 = edge_index is int64, 0 = int32
__device__ __forceinline__ float loadf(const void* p, size_t i, int isbf) {
    return isbf ? bf2f(((const unsigned short*)p)[i]) : ((const float*)p)[i];
}
__device__ __forceinline__ int loadi(const void* p, size_t i, int is64) {
    return is64 ? (int)(((const long long*)p)[i]) : ((const int*)p)[i];
}

// ---- dtype detection + gcur init (merged; 1 block x 512) ----
__global__ void k_detect(const unsigned int* __restrict__ xb,
                         const unsigned int* __restrict__ eib,
                         int* __restrict__ flags, int* __restrict__ gcur) {
    int tid = threadIdx.x;
    if (tid < NB) gcur[tid] = tid * CAP;
    if (tid < 64) {  // whole wave 0: ballots are wave-local
        unsigned int u = xb[tid];
        unsigned int lo_exp = (u >> 7) & 0xFF;
        bool bfplaus = (lo_exp >= 100 && lo_exp <= 140) || ((u & 0xFFFFu) == 0u);
        unsigned long long m1 = __ballot(bfplaus);
        unsigned int hi = eib[2 * tid + 1];
        unsigned long long m2 = __ballot(hi == 0u);
        if (tid == 0) {
            flags[0] = (__popcll(m1) >= 48) ? 1 : 0;
            flags[1] = (m2 == 0xFFFFFFFFFFFFFFFFULL) ? 1 : 0;
        }
    }
}

// ---- phase 1: barrier-free LDS-staged multi-split into fixed-capacity dst-buckets ----
// binned[p] = (dst_local << 24) | src
__global__ __launch_bounds__(256) void k_bin(const void* __restrict__ ei,
                                             int* __restrict__ gcur,
                                             unsigned int* __restrict__ binned,
                                             const int* __restrict__ flags, int E) {
    __shared__ unsigned int lbuf[NB * DSTRIDE];  // ~39 KB
    __shared__ int lcnt[NB];
    __shared__ int pcur[NB];
    int is64 = flags[1];
    int tid = threadIdx.x;
    for (int b = tid; b < NB; b += 256) lcnt[b] = 0;
    __syncthreads();
    int per = (E + gridDim.x - 1) / gridDim.x;
    int e0 = blockIdx.x * per;
    int e1 = min(e0 + per, E);
    // classify: NO barriers in this loop
    for (int e = e0 + tid; e < e1; e += 256) {
        int s = loadi(ei, e, is64);
        int d = loadi(ei, (size_t)N_EDGES + e, is64);
        int b = d >> 8;
        unsigned int val = ((unsigned int)(d & 255) << 24) | (unsigned int)s;
        int slot = atomicAdd(&lcnt[b], 1);
        if (slot < DEPTH) {
            lbuf[b * DSTRIDE + slot] = val;
        } else {  // rare overflow: direct write
            int p = atomicAdd(&gcur[b], 1);
            if (p < (b + 1) * CAP) binned[p] = val;
        }
    }
    __syncthreads();
    // reserve drain regions (all atomics pipelined)
    for (int b = tid; b < NB; b += 256) {
        int c = min(lcnt[b], DEPTH);
        pcur[b] = c ? atomicAdd(&gcur[b], c) : 0;
    }
    __syncthreads();
    // wave-cooperative drain: lane j copies entry j of each bucket
    int lane = tid & 63, wv = tid >> 6;
    for (int b = wv; b < NB; b += 4) {
        int c = min(lcnt[b], DEPTH);
        if (lane < c) {
            int p = pcur[b] + lane;
            if (p < (b + 1) * CAP) binned[p] = lbuf[b * DSTRIDE + lane];
        }
    }
}

// ---- scan bucket totals -> btot (exclusive), rs[N]=E ----
__global__ void k_bscan(const int* __restrict__ gcur, int* __restrict__ btot,
                        int* __restrict__ rs) {
    __shared__ int sh[512];
    int t = threadIdx.x;
    int v = 0;
    if (t < NB) {
        v = gcur[t] - t * CAP;
        if (v > CAP) v = CAP;
    }
    sh[t] = v;
    __syncthreads();
    for (int o = 1; o < 512; o <<= 1) {
        int u = (t >= o) ? sh[t - o] : 0;
        __syncthreads();
        sh[t] += u;
        __syncthreads();
    }
    if (t < NB) btot[t] = sh[t] - v;
    if (t == NB) rs[N_NODES] = N_EDGES;
}

// ---- phase 2: per bucket, count per node, scan, write rs/dinv + exact CSR ----
__global__ __launch_bounds__(512) void k_regroup(const unsigned int* __restrict__ binned,
                                                 const int* __restrict__ btot,
                                                 const int* __restrict__ gcur,
                                                 int* __restrict__ csr_src,
                                                 int* __restrict__ rs,
                                                 float* __restrict__ dinv) {
    __shared__ int lcnt[256];
    __shared__ int lofs[256];
    int b = blockIdx.x, tid = threadIdx.x;
    int n0 = b * 256;
    int nn = min(256, N_NODES - n0);
    if (tid < 256) lcnt[tid] = 0;
    __syncthreads();
    int src0 = b * CAP;
    int m = gcur[b] - src0;
    if (m > CAP) m = CAP;
    for (int i = tid; i < m; i += 512) {
        atomicAdd(&lcnt[binned[src0 + i] >> 24], 1);
    }
    __syncthreads();
    int c = 0;
    if (tid < 256) { c = lcnt[tid]; lofs[tid] = c; }
    __syncthreads();
    for (int o = 1; o < 256; o <<= 1) {
        int u = (tid < 256 && tid >= o) ? lofs[tid - o] : 0;
        __syncthreads();
        if (tid < 256) lofs[tid] += u;
        __syncthreads();
    }
    int base = btot[b];
    if (tid < 256) {
        int mystart = base + lofs[tid] - c;
        if (tid < nn) {
            rs[n0 + tid] = mystart;
            dinv[n0 + tid] = rsqrtf(1.0f + (float)c);
        }
        lofs[tid] = mystart;  // reuse as cursors
    }
    __syncthreads();
    for (int i = tid; i < m; i += 512) {
        unsigned int v = binned[src0 + i];
        int p = atomicAdd(&lofs[v >> 24], 1);
        csr_src[p] = v & 0xFFFFFF;
    }
}

// ---- MFMA GEMM1: g[N,64] = bf16( dinv[r] * (x[N,128] @ W1[128,64]) ) ----
__global__ __launch_bounds__(256) void k_gemm1(const void* __restrict__ x,
                                               const void* __restrict__ W1,
                                               const float* __restrict__ dinv,
                                               unsigned short* __restrict__ out,
                                               const int* __restrict__ flags, int n) {
    __shared__ unsigned short W1T[64 * 136];
    int isbf = flags[0];
    int tid = threadIdx.x;
    for (int i = tid; i < IN_DIM * HID_DIM; i += 256) {
        int k = i >> 6, nn = i & 63;
        W1T[nn * 136 + k] = isbf ? ((const unsigned short*)W1)[i] : f2bf(((const float*)W1)[i]);
    }
    __syncthreads();
    int lane = tid & 63;
    int lane16 = lane & 15, quad = lane >> 4;
    bf16x8 bfrag[4][4];
#pragma unroll
    for (int ct = 0; ct < 4; ++ct)
#pragma unroll
        for (int kc = 0; kc < 4; ++kc)
            bfrag[ct][kc] = *(const bf16x8*)&W1T[(ct * 16 + lane16) * 136 + kc * 32 + quad * 8];
    int wid = (blockIdx.x * 256 + tid) >> 6;
    int nw = (gridDim.x * 256) >> 6;
    for (int t = wid; t < NTILES; t += nw) {
        int row0 = t * 16;
        bf16x8 afrag[4];
        if (isbf) {
            const unsigned short* xr = (const unsigned short*)x + (size_t)(row0 + lane16) * IN_DIM;
#pragma unroll
            for (int kc = 0; kc < 4; ++kc)
                afrag[kc] = *(const bf16x8*)(xr + kc * 32 + quad * 8);
        } else {
            const float* xr = (const float*)x + (size_t)(row0 + lane16) * IN_DIM;
#pragma unroll
            for (int kc = 0; kc < 4; ++kc) {
                f32x4 p0 = *(const f32x4*)(xr + kc * 32 + quad * 8);
                f32x4 p1 = *(const f32x4*)(xr + kc * 32 + quad * 8 + 4);
                bf16x8 a;
#pragma unroll
                for (int j = 0; j < 4; ++j) {
                    a[j] = (short)f2bf(p0[j]);
                    a[4 + j] = (short)f2bf(p1[j]);
                }
                afrag[kc] = a;
            }
        }
        f32x4 acc[4] = {};
#pragma unroll
        for (int kc = 0; kc < 4; ++kc)
#pragma unroll
            for (int ct = 0; ct < 4; ++ct)
                acc[ct] = __builtin_amdgcn_mfma_f32_16x16x32_bf16(afrag[kc], bfrag[ct][kc], acc[ct], 0, 0, 0);
        float dv[4];
#pragma unroll
        for (int r = 0; r < 4; ++r) dv[r] = dinv[row0 + quad * 4 + r];
#pragma unroll
        for (int ct = 0; ct < 4; ++ct)
#pragma unroll
            for (int r = 0; r < 4; ++r)
                out[(size_t)(row0 + quad * 4 + r) * HID_DIM + ct * 16 + lane16] = f2bf(acc[ct][r] * dv[r]);
    }
}

// gather aggregation v3: 8 lanes/edge, 16B loads, 4-deep explicit gather pipeline
// (32 edges' loads in flight per wave chunk); bf16 out
// out[d] = bf16( dinv[d] * ( g[d] + sum_{s in row d} g[s] ) ), g pre-scaled by dinv[s]
__global__ __launch_bounds__(256) void k_aggregate(const unsigned short* __restrict__ g,
                                                   const float* __restrict__ dinv,
                                                   const int* __restrict__ rs,
                                                   const int* __restrict__ csr_src,
                                                   unsigned short* __restrict__ out, int n) {
    int lane = threadIdx.x & 63;
    int grp = lane >> 3;   // edge slot (0..7)
    int sub = lane & 7;    // 16B chunk of the row (0..7)
    int node = blockIdx.x * 4 + (threadIdx.x >> 6);
    if (node >= n) return;
    int start = rs[node];
    int m_all = rs[node + 1] - start;
    const u32x4* g4 = (const u32x4*)g;
    float acc[8] = {0.f, 0.f, 0.f, 0.f, 0.f, 0.f, 0.f, 0.f};
    for (int base = 0; base < m_all; base += 64) {
        int m = min(64, m_all - base);
        int idx = (lane < m) ? csr_src[start + base + lane] : 0;
        int nIt = (m + 7) >> 3;
        for (int it0 = 0; it0 < nIt; it0 += 4) {
            // issue 4 independent gathers before accumulating (dummy = own row, w=0)
            u32x4 P[4];
            float w[4];
#pragma unroll
            for (int k = 0; k < 4; ++k) {
                int j = (it0 + k) * 8 + grp;   // <= 63 always
                int s = __shfl(idx, j & 63);
                bool act = (j < m);
                w[k] = act ? 1.0f : 0.0f;
                P[k] = g4[(size_t)(act ? s : node) * 8 + sub];
            }
#pragma unroll
            for (int k = 0; k < 4; ++k)
#pragma unroll
                for (int q = 0; q < 4; ++q) {
                    unsigned int u = P[k][q];
                    acc[2 * q]     = fmaf(w[k], u32f(u << 16), acc[2 * q]);
                    acc[2 * q + 1] = fmaf(w[k], u32f(u & 0xFFFF0000u), acc[2 * q + 1]);
                }
        }
    }
#pragma unroll
    for (int off = 8; off <= 32; off <<= 1)
#pragma unroll
        for (int q = 0; q < 8; ++q) acc[q] += __shfl_xor(acc[q], off);
    if (grp == 0) {  // lanes 0..7 hold the full row: lane sub -> cols sub*8..sub*8+7
        u32x4 ps = g4[(size_t)node * 8 + sub];
        float dd = dinv[node];
        u32x4 ov;
#pragma unroll
        for (int q = 0; q < 4; ++q) {
            float lo = (acc[2 * q]     + u32f(ps[q] << 16)) * dd;
            float hi = (acc[2 * q + 1] + u32f(ps[q] & 0xFFFF0000u)) * dd;
            ov[q] = (unsigned int)f2bf(lo) | ((unsigned int)f2bf(hi) << 16);
        }
        ((u32x4*)out)[(size_t)node * 8 + sub] = ov;
    }
}

// ---- MFMA GEMM2: g2[N,64] = bf16( dinv[r] * (relu(in[N,64]+b1) @ W2[64,64]) ), in is bf16 ----
__global__ __launch_bounds__(256) void k_gemm2(const unsigned short* __restrict__ in,
                                               const void* __restrict__ W2,
                                               const void* __restrict__ b1,
                                               const float* __restrict__ dinv,
                                               unsigned short* __restrict__ out,
                                               const int* __restrict__ flags, int n) {
    __shared__ unsigned short W2T[64 * 72];
    __shared__ float bs[64];
    int isbf = flags[0];
    int tid = threadIdx.x;
    for (int i = tid; i < HID_DIM * EMB_DIM; i += 256) {
        int k = i >> 6, nn = i & 63;
        W2T[nn * 72 + k] = isbf ? ((const unsigned short*)W2)[i] : f2bf(((const float*)W2)[i]);
    }
    if (tid < 64) bs[tid] = loadf(b1, tid, isbf);
    __syncthreads();
    int lane = tid & 63;
    int lane16 = lane & 15, quad = lane >> 4;
    bf16x8 bfrag[4][2];
#pragma unroll
    for (int ct = 0; ct < 4; ++ct)
#pragma unroll
        for (int kc = 0; kc < 2; ++kc)
            bfrag[ct][kc] = *(const bf16x8*)&W2T[(ct * 16 + lane16) * 72 + kc * 32 + quad * 8];
    float bv[2][8];
#pragma unroll
    for (int kc = 0; kc < 2; ++kc)
#pragma unroll
        for (int j = 0; j < 8; ++j) bv[kc][j] = bs[kc * 32 + quad * 8 + j];
    int wid = (blockIdx.x * 256 + tid) >> 6;
    int nw = (gridDim.x * 256) >> 6;
    for (int t = wid; t < NTILES; t += nw) {
        int row0 = t * 16;
        const unsigned short* ir = in + (size_t)(row0 + lane16) * HID_DIM;
        bf16x8 afrag[2];
#pragma unroll
        for (int kc = 0; kc < 2; ++kc) {
            bf16x8 raw = *(const bf16x8*)(ir + kc * 32 + quad * 8);
            bf16x8 a;
#pragma unroll
            for (int j = 0; j < 8; ++j) {
                float f = fmaxf(bf2f((unsigned short)raw[j]) + bv[kc][j], 0.0f);
                a[j] = (short)f2bf(f);
            }
            afrag[kc] = a;
        }
        f32x4 acc[4] = {};
#pragma unroll
        for (int kc = 0; kc < 2; ++kc)
#pragma unroll
            for (int ct = 0; ct < 4; ++ct)
                acc[ct] = __builtin_amdgcn_mfma_f32_16x16x32_bf16(afrag[kc], bfrag[ct][kc], acc[ct], 0, 0, 0);
        float dv[4];
#pragma unroll
        for (int r = 0; r < 4; ++r) dv[r] = dinv[row0 + quad * 4 + r];
#pragma unroll
        for (int ct = 0; ct < 4; ++ct)
#pragma unroll
            for (int r = 0; r < 4; ++r)
                out[(size_t)(row0 + quad * 4 + r) * EMB_DIM + ct * 16 + lane16] = f2bf(acc[ct][r] * dv[r]);
    }
}

// ---- MFMA head: logits = (in+b2) @ Wl + bl ; log_softmax ; in is bf16 ----
__global__ __launch_bounds__(256) void k_final(const unsigned short* __restrict__ in,
                                               const void* __restrict__ b2,
                                               const void* __restrict__ Wl,
                                               const void* __restrict__ bl,
                                               void* __restrict__ out,
                                               const int* __restrict__ flags, int n) {
    __shared__ unsigned short WlT[48 * 72];
    __shared__ float b2s[64];
    int isbf = flags[0];
    int tid = threadIdx.x;
    for (int i = tid; i < 48 * 64; i += 256) {
        int nn = i >> 6, k = i & 63;
        WlT[nn * 72 + k] = (nn < OUT_DIM) ?
            (isbf ? ((const unsigned short*)Wl)[k * OUT_DIM + nn] : f2bf(((const float*)Wl)[k * OUT_DIM + nn]))
            : (unsigned short)0;
    }
    if (tid < 64) b2s[tid] = loadf(b2, tid, isbf);
    __syncthreads();
    int lane = tid & 63;
    int lane16 = lane & 15, quad = lane >> 4;
    bf16x8 bfrag[3][2];
#pragma unroll
    for (int ct = 0; ct < 3; ++ct)
#pragma unroll
        for (int kc = 0; kc < 2; ++kc)
            bfrag[ct][kc] = *(const bf16x8*)&WlT[(ct * 16 + lane16) * 72 + kc * 32 + quad * 8];
    float b2v[2][8];
#pragma unroll
    for (int kc = 0; kc < 2; ++kc)
#pragma unroll
        for (int j = 0; j < 8; ++j) b2v[kc][j] = b2s[kc * 32 + quad * 8 + j];
    float blv[3];
    bool v2 = (lane16 < 8);
#pragma unroll
    for (int ct = 0; ct < 3; ++ct) {
        int col = ct * 16 + lane16;
        blv[ct] = (col < OUT_DIM) ? loadf(bl, col, isbf) : 0.0f;
    }
    int wid = (blockIdx.x * 256 + tid) >> 6;
    int nw = (gridDim.x * 256) >> 6;
    for (int t = wid; t < NTILES; t += nw) {
        int row0 = t * 16;
        const unsigned short* ir = in + (size_t)(row0 + lane16) * EMB_DIM;
        bf16x8 afrag[2];
#pragma unroll
        for (int kc = 0; kc < 2; ++kc) {
            bf16x8 raw = *(const bf16x8*)(ir + kc * 32 + quad * 8);
            bf16x8 a;
#pragma unroll
            for (int j = 0; j < 8; ++j) {
                float f = bf2f((unsigned short)raw[j]) + b2v[kc][j];
                a[j] = (short)f2bf(f);
            }
            afrag[kc] = a;
        }
        f32x4 acc[3] = {};
#pragma unroll
        for (int kc = 0; kc < 2; ++kc)
#pragma unroll
            for (int ct = 0; ct < 3; ++ct)
                acc[ct] = __builtin_amdgcn_mfma_f32_16x16x32_bf16(afrag[kc], bfrag[ct][kc], acc[ct], 0, 0, 0);
#pragma unroll
        for (int r = 0; r < 4; ++r) {
            float l0 = acc[0][r] + blv[0];
            float l1 = acc[1][r] + blv[1];
            float l2 = v2 ? (acc[2][r] + blv[2]) : -INFINITY;
            float mx = fmaxf(fmaxf(l0, l1), l2);
#pragma unroll
            for (int s = 1; s < 16; s <<= 1) mx = fmaxf(mx, __shfl_xor(mx, s));
            float sm = expf(l0 - mx) + expf(l1 - mx) + (v2 ? expf(l2 - mx) : 0.0f);
#pragma unroll
            for (int s = 1; s < 16; s <<= 1) sm += __shfl_xor(sm, s);
            float ls = mx + logf(sm);
            int row = row0 + quad * 4 + r;
            size_t o = (size_t)row * OUT_DIM;
            if (isbf) {
                __hip_bfloat16* ob = (__hip_bfloat16*)out;
                ob[o + lane16] = __float2bfloat16(l0 - ls);
                ob[o + 16 + lane16] = __float2bfloat16(l1 - ls);
                if (v2) ob[o + 32 + lane16] = __float2bfloat16(l2 - ls);
            } else {
                float* of = (float*)out;
                of[o + lane16] = l0 - ls;
                of[o + 16 + lane16] = l1 - ls;
                if (v2) of[o + 32 + lane16] = l2 - ls;
            }
        }
    }
}

extern "C" void kernel_launch(void* const* d_in, const int* in_sizes, int n_in,
                              void* d_out, int out_size, void* d_ws, size_t ws_size,
                              hipStream_t stream) {
    const void* x  = d_in[0];
    const void* ei = d_in[1];
    const void* W1 = d_in[2];
    const void* b1 = d_in[3];
    const void* W2 = d_in[4];
    const void* b2 = d_in[5];
    const void* Wl = d_in[6];
    const void* bl = d_in[7];

    float* ws = (float*)d_ws;
    // FROZEN layout (float-slot offsets). N*64 bf16 = 6.4M ushorts = 3,200,000 FLOAT slots.
    int*   flags   = (int*)ws;                             // [0, 64)
    float* dinv    = ws + 64;                              // [64, 100064) pad -> 100096
    int*   rs      = (int*)(ws + 100096);                  // N+1 ints, pad -> 200224
    int*   btot    = (int*)(ws + 200224);                  // [200224, 200736)
    int*   gcur    = (int*)(ws + 200736);                  // [200736, 201248)
    int*   csr_src = (int*)(ws + 201248);                  // E ints -> [201248, 1801248)
    unsigned short* g      = (unsigned short*)(ws + 1801248); // bf16 [1801248, 5001248)
    unsigned short* aggout = (unsigned short*)(ws + 5001248); // bf16 [5001248, 8201248)
    unsigned int* binned   = (unsigned int*)(ws + 1801248);   // NB*CAP ints [1801248, 3803168)
                                                              // aliases g only; dead before k_gemm1
    // total ws: 8,201,248 floats = 32.8 MB

    // detect + gcur init (merged)
    k_detect<<<1, 512, 0, stream>>>((const unsigned int*)x, (const unsigned int*)ei, flags, gcur);

    // CSR build: bin (barrier-free) -> bucket scan -> regroup (counts+scan+fill+rs+dinv)
    k_bin<<<512, 256, 0, stream>>>(ei, gcur, binned, flags, N_EDGES);
    k_bscan<<<1, 512, 0, stream>>>(gcur, btot, rs);
    k_regroup<<<NB, 512, 0, stream>>>(binned, btot, gcur, csr_src, rs, dinv);

    // layer 1
    k_gemm1<<<1280, 256, 0, stream>>>(x, W1, dinv, g, flags, N_NODES);
    k_aggregate<<<25000, 256, 0, stream>>>(g, dinv, rs, csr_src, aggout, N_NODES);

    // layer 2
    k_gemm2<<<1280, 256, 0, stream>>>(aggout, W2, b1, dinv, g, flags, N_NODES);
    k_aggregate<<<25000, 256, 0, stream>>>(g, dinv, rs, csr_src, aggout, N_NODES);

    // head
    k_final<<<1280, 256, 0, stream>>>(aggout, b2, Wl, bl, d_out, flags, N_NODES);
}